// Round 8
// baseline (303.229 us; speedup 1.0000x reference)
//
#include <hip/hip_runtime.h>

// R20: barrier-free gathers via register shuffle broadcast. Per-edge staged
// values (src, exp[6], wg / wa) stay in the staging lane's REGISTERS; the
// inner loop broadcasts edge j's values with __shfl(x, j) (loop-uniform index,
// wave-synchronous by architecture — no LDS, no fences, none of R13's
// visibility hazard). Deletes all __syncthreads + the mc_sh max-of-4-nodes
// coupling (each wave runs exactly its own degree; ~30% padding removed) in
// k_gatgcn and k_arma. Load pattern unchanged (proven R12 shape).
// Rest verbatim R19/R18. 12 launches.

#define NN 20000
#define EE 320000
#define GATD 384
#define NH 6
#define OUTD 64
#define ODIM 576

typedef __bf16 bf16_8 __attribute__((ext_vector_type(8)));
typedef float f32_4 __attribute__((ext_vector_type(4)));

__device__ __forceinline__ float lrelu(float x, float s) { return x > 0.f ? x : s * x; }

__device__ __forceinline__ float loadf(const void* p, size_t i, int f32) {
  return f32 ? ((const float*)p)[i] : (float)((const __bf16*)p)[i];
}

// ---------- fused dtype probes ----------
struct ProbeArgs {
  const void* ptr[15];
  int cnt[15];
  int flagidx[15];
  const int* ei;
};
__global__ void k_probe_all(ProbeArgs a, int* __restrict__ flags) {
  __shared__ int cnt;
  if (threadIdx.x == 0) cnt = 0;
  __syncthreads();
  int b = blockIdx.x;
  if (b < 15) {
    const unsigned short* u = (const unsigned short*)a.ptr[b];
    int m = a.cnt[b] < 2048 ? a.cnt[b] : 2048;
    int c = 0;
    for (int i = threadIdx.x; i < m; i += 256) {
      float v = __uint_as_float(((unsigned int)u[i]) << 16);
      if (!(fabsf(v) < 1e4f)) c++;
    }
    if (c) atomicAdd(&cnt, c);
    __syncthreads();
    if (threadIdx.x == 0) flags[a.flagidx[b]] = (cnt > m / 16) ? 1 : 0;
  } else {
    int c = 0;
    for (int i = threadIdx.x; i < 1024; i += 256)
      if (a.ei[2 * i + 1] != 0) c++;
    if (c) atomicAdd(&cnt, c);
    __syncthreads();
    if (threadIdx.x == 0) flags[16] = (cnt <= 2) ? 1 : 0;
  }
}

// ---------- merged small conversions + weight cvt/transpose ----------
struct CvtSeg { const void* in; __bf16* out; int n; int flagidx; int blk0; };
struct CvtArgs { CvtSeg s[7]; };
struct TSeg { const void* in; __bf16* out; int R; int C; int flagidx; int blk0; };
struct TArgs { TSeg s[6]; };
__global__ void k_cvt_merged(CvtArgs ca, int ncvtblk, TArgs ta, const int* __restrict__ flags) {
  if ((int)blockIdx.x < ncvtblk) {
    int b = blockIdx.x;
    int k = 0;
    while (k + 1 < 7 && ca.s[k + 1].blk0 <= b) k++;
    const CvtSeg sg = ca.s[k];
    int i = (b - sg.blk0) * 256 + threadIdx.x;
    if (i >= sg.n) return;
    sg.out[i] = flags[sg.flagidx] ? (__bf16)((const float*)sg.in)[i] : ((const __bf16*)sg.in)[i];
    return;
  }
  __shared__ float t[32][33];
  int b = blockIdx.x - ncvtblk;
  int k = 0;
  while (k + 1 < 6 && ta.s[k + 1].blk0 <= b) k++;
  const TSeg sg = ta.s[k];
  int f32 = flags[sg.flagidx];
  int tpx = (sg.C + 31) >> 5;
  int lt = b - sg.blk0;
  int c0 = (lt % tpx) * 32, r0 = (lt / tpx) * 32;
  int tid = threadIdx.x;
  for (int idx = tid; idx < 1024; idx += 256) {
    int r = idx >> 5, c = idx & 31;
    if (r0 + r < sg.R && c0 + c < sg.C)
      t[r][c] = loadf(sg.in, (size_t)(r0 + r) * sg.C + (c0 + c), f32);
  }
  __syncthreads();
  for (int idx = tid; idx < 1024; idx += 256) {
    int r = idx >> 5, c = idx & 31;
    if (c0 + r < sg.C && r0 + c < sg.R)
      sg.out[(size_t)(c0 + r) * sg.R + (r0 + c)] = (__bf16)t[c][r];
  }
}

// ---------- CSR build ----------
__global__ void k_count(const int* __restrict__ ei, const void* __restrict__ ew,
                        const int* __restrict__ flags,
                        int* __restrict__ deg, float* __restrict__ wdeg) {
  int e = blockIdx.x * 256 + threadIdx.x;
  if (e >= EE) return;
  int sh = flags[16];
  int d = ei[(size_t)(EE + e) << sh];
  atomicAdd(&deg[d], 1);
  atomicAdd(&wdeg[d], loadf(ew, e, flags[2]));
}

// parallel coalesced scan, phase 1: per-block sums of deg
__global__ __launch_bounds__(256) void k_scan1(const int* __restrict__ deg,
                                               int* __restrict__ bsum) {
  int i = blockIdx.x * 256 + threadIdx.x;
  int v = (i < NN) ? deg[i] : 0;
  for (int off = 32; off; off >>= 1) v += __shfl_xor(v, off);
  __shared__ int ws[4];
  if ((threadIdx.x & 63) == 0) ws[threadIdx.x >> 6] = v;
  __syncthreads();
  if (threadIdx.x == 0) bsum[blockIdx.x] = ws[0] + ws[1] + ws[2] + ws[3];
}

// phase 2: base reduce + in-block shuffle scan + rowstart + dinv tail
__global__ __launch_bounds__(256) void k_scan2(const int* __restrict__ deg,
    const int* __restrict__ bsum, const float* __restrict__ wdeg,
    int* __restrict__ rowstart, float* __restrict__ dg, float* __restrict__ da) {
  int b = blockIdx.x;
  int tid = threadIdx.x;
  int lane = tid & 63, wv = tid >> 6;
  int i = b * 256 + tid;
  __shared__ int red[4];
  __shared__ int wsum2[4];
  __shared__ int sbase;
  {
    int v = (tid < b) ? bsum[tid] : 0;
    for (int off = 32; off; off >>= 1) v += __shfl_xor(v, off);
    if (lane == 0) red[wv] = v;
    __syncthreads();
    if (tid == 0) sbase = red[0] + red[1] + red[2] + red[3];
    __syncthreads();
  }
  int v = (i < NN) ? deg[i] : 0;
  int run = v;
  for (int off = 1; off < 64; off <<= 1) {
    int u = __shfl_up(run, off);
    if (lane >= off) run += u;
  }
  if (lane == 63) wsum2[wv] = run;
  __syncthreads();
  int wb = 0;
#pragma unroll
  for (int w = 0; w < 4; w++) { int x = wsum2[w]; if (w < wv) wb += x; }
  int excl = sbase + wb + run - v;
  if (i < NN) rowstart[i] = excl;
  if (i == NN - 1) rowstart[NN] = excl + v;
  if (i < NN) {
    float w = wdeg[i];
    dg[i] = rsqrtf(w + 1.0f);
    da[i] = w > 0.f ? rsqrtf(w) : 0.f;
  }
}

__global__ void k_fill(const int* __restrict__ ei, const void* __restrict__ ew,
                       const int* __restrict__ flags, const int* __restrict__ rowstart,
                       int* __restrict__ cursor,
                       int* __restrict__ csr_src, float* __restrict__ csr_w) {
  int e = blockIdx.x * 256 + threadIdx.x;
  if (e >= EE) return;
  int sh = flags[16];
  int d = ei[(size_t)(EE + e) << sh];
  int s = ei[(size_t)e << sh];
  int pos = rowstart[d] + atomicAdd(&cursor[d], 1);
  csr_src[pos] = s;
  csr_w[pos] = loadf(ew, e, flags[2]);
}

// ---------- MFMA GEMM: 64x128 tile, dual output ---------- (R16/R18 verbatim)
template<bool HAS_BIAS>
__global__ __launch_bounds__(256) void gemm64(const void* __restrict__ A,
    const int* __restrict__ aflag, const __bf16* __restrict__ Bt,
    const __bf16* __restrict__ bias,
    __bf16* __restrict__ C1, int n1, int ldc1,
    __bf16* __restrict__ C2, int ldc2,
    int M, int K) {
  __shared__ __bf16 Al[64][40];
  __shared__ __bf16 Bl[128][40];
  int a32 = *aflag;
  int tid = threadIdx.x;
  int w = tid >> 6, lane = tid & 63;
  int quad = lane >> 4, r = lane & 15;
  int row0 = blockIdx.x * 64, col0 = blockIdx.y * 128;
  f32_4 acc[4][2] = {};
  int srow = tid >> 2;
  int koff = (tid & 3) * 8;
  int brow = tid >> 1;
  int bko  = (tid & 1) * 16;
  for (int kt = 0; kt < K; kt += 32) {
    int arow = row0 + srow;
    if (a32) {
      float4 a0 = {0.f, 0.f, 0.f, 0.f}, a1 = {0.f, 0.f, 0.f, 0.f};
      if (arow < M) {
        const float* ap = (const float*)A + (size_t)arow * K + kt + koff;
        a0 = *(const float4*)ap;
        a1 = *(const float4*)(ap + 4);
      }
      bf16_8 t;
      t[0] = (__bf16)a0.x; t[1] = (__bf16)a0.y; t[2] = (__bf16)a0.z; t[3] = (__bf16)a0.w;
      t[4] = (__bf16)a1.x; t[5] = (__bf16)a1.y; t[6] = (__bf16)a1.z; t[7] = (__bf16)a1.w;
      *(bf16_8*)(&Al[srow][koff]) = t;
    } else {
      float4 av = {0.f, 0.f, 0.f, 0.f};
      if (arow < M) av = *(const float4*)((const __bf16*)A + (size_t)arow * K + kt + koff);
      *(float4*)(&Al[srow][koff]) = av;
    }
    const __bf16* bp = Bt + (size_t)(col0 + brow) * K + kt + bko;
    *(float4*)(&Bl[brow][bko])     = *(const float4*)bp;
    *(float4*)(&Bl[brow][bko + 8]) = *(const float4*)(bp + 8);
    __syncthreads();
    bf16_8 bfrag0 = *(const bf16_8*)(&Bl[w * 16 + r][quad * 8]);
    bf16_8 bfrag1 = *(const bf16_8*)(&Bl[64 + w * 16 + r][quad * 8]);
#pragma unroll
    for (int mt = 0; mt < 4; mt++) {
      bf16_8 afrag = *(const bf16_8*)(&Al[mt * 16 + r][quad * 8]);
      acc[mt][0] = __builtin_amdgcn_mfma_f32_16x16x32_bf16(afrag, bfrag0, acc[mt][0], 0, 0, 0);
      acc[mt][1] = __builtin_amdgcn_mfma_f32_16x16x32_bf16(afrag, bfrag1, acc[mt][1], 0, 0, 0);
    }
    __syncthreads();
  }
  __bf16* Cp; int ldc; int cbase;
  if (col0 < n1) { Cp = C1; ldc = ldc1; cbase = col0; }
  else           { Cp = C2; ldc = ldc2; cbase = col0 - n1; }
  int cc0 = cbase + w * 16 + r;
  int cc1 = cbase + 64 + w * 16 + r;
  float bv0 = HAS_BIAS ? (float)bias[col0 + w * 16 + r] : 0.0f;
  float bv1 = HAS_BIAS ? (float)bias[col0 + 64 + w * 16 + r] : 0.0f;
#pragma unroll
  for (int mt = 0; mt < 4; mt++) {
#pragma unroll
    for (int rr = 0; rr < 4; rr++) {
      int crow = row0 + mt * 16 + quad * 4 + rr;
      if (crow < M) {
        Cp[(size_t)crow * ldc + cc0] = (__bf16)(acc[mt][0][rr] + bv0);
        Cp[(size_t)crow * ldc + cc1] = (__bf16)(acc[mt][1][rr] + bv1);
      }
    }
  }
}

// ---------- attention logits: wave per (node,head) ---------- (R12 verbatim)
__global__ void k_alar_w(const __bf16* __restrict__ xwb, const __bf16* __restrict__ as_,
                         const __bf16* __restrict__ ad_,
                         float* __restrict__ al, float* __restrict__ ar) {
  int p = blockIdx.x * 4 + (threadIdx.x >> 6);
  int lane = threadIdx.x & 63;
  if (p >= NN * NH) return;
  int i = p / NH, h = p - i * NH;
  float xv = (float)xwb[(size_t)i * GATD + h * OUTD + lane];
  float s1 = xv * (float)as_[h * OUTD + lane];
  float s2 = xv * (float)ad_[h * OUTD + lane];
  for (int off = 32; off; off >>= 1) { s1 += __shfl_xor(s1, off); s2 += __shfl_xor(s2, off); }
  if (lane == 0) { al[p] = s1; ar[p] = s2; }
}

// ---------- fused GAT + GCN0/1: wave per node, shuffle-broadcast gather ----------
// No LDS, no barriers, no cross-wave coupling: staged edge data lives in the
// staging lane's registers; inner loop broadcasts via __shfl(x, j) (uniform j).
__global__ __launch_bounds__(256) void k_gatgcn(const __bf16* __restrict__ xwb,
    const __bf16* __restrict__ xwgb,
    const float* __restrict__ al, const float* __restrict__ ar,
    const int* __restrict__ rowstart, const int* __restrict__ csr_src,
    const float* __restrict__ csr_w, const float* __restrict__ dgcn,
    const __bf16* __restrict__ bgat, const __bf16* __restrict__ b0,
    const __bf16* __restrict__ b1,
    __bf16* __restrict__ h1b, float* __restrict__ out) {
  int wv = threadIdx.x >> 6, lane = threadIdx.x & 63;
  int i = blockIdx.x * 4 + wv;           // NN % 4 == 0
  int e0 = rowstart[i], e1 = rowstart[i + 1];
  int nch = (e1 - e0 + 63) >> 6;
  float arv[NH], exs[NH], acc[NH], denp[NH];
#pragma unroll
  for (int h = 0; h < NH; h++) arv[h] = ar[i * NH + h];
#pragma unroll
  for (int h = 0; h < NH; h++) {
    float e = lrelu(al[i * NH + h] + arv[h], 0.2f);
    exs[h] = __expf(e);                  // self-loop weight
    acc[h] = exs[h] * (float)xwb[(size_t)i * GATD + h * OUTD + lane];
    denp[h] = 0.f;
  }
  float g0 = 0.f, g1 = 0.f;
  for (int c = 0; c < nch; c++) {
    int base = e0 + c * 64;
    int cnt = e1 - base; cnt = cnt > 64 ? 64 : cnt;
    int s = i; float wg = 0.f;
    float exh[NH];
#pragma unroll
    for (int h = 0; h < NH; h++) exh[h] = 0.f;
    if (lane < cnt) {
      int eidx = base + lane;
      s = csr_src[eidx];
      wg = dgcn[s] * csr_w[eidx];
#pragma unroll
      for (int h = 0; h < NH; h++)
        exh[h] = __expf(lrelu(al[s * NH + h] + arv[h], 0.2f));
    }
#pragma unroll
    for (int h = 0; h < NH; h++) denp[h] += exh[h];
    int j = 0;
    for (; j + 2 <= cnt; j += 2) {
      int s0 = __shfl(s, j), s1 = __shfl(s, j + 1);
      float wg0 = __shfl(wg, j), wg1 = __shfl(wg, j + 1);
      float e0h[NH], e1h[NH];
#pragma unroll
      for (int h = 0; h < NH; h++) { e0h[h] = __shfl(exh[h], j); e1h[h] = __shfl(exh[h], j + 1); }
      const __bf16* r0 = xwb + (size_t)s0 * GATD + lane;
      const __bf16* r1 = xwb + (size_t)s1 * GATD + lane;
      const __bf16* p0 = xwgb + (size_t)s0 * 128;
      const __bf16* p1 = xwgb + (size_t)s1 * 128;
      float x0[NH], x1[NH];
#pragma unroll
      for (int h = 0; h < NH; h++) { x0[h] = (float)r0[h * OUTD]; x1[h] = (float)r1[h * OUTD]; }
      float y00 = (float)p0[lane], y01 = (float)p0[lane + 64];
      float y10 = (float)p1[lane], y11 = (float)p1[lane + 64];
#pragma unroll
      for (int h = 0; h < NH; h++)
        acc[h] += e0h[h] * x0[h] + e1h[h] * x1[h];
      g0 += wg0 * y00 + wg1 * y10;
      g1 += wg0 * y01 + wg1 * y11;
    }
    if (j < cnt) {
      int s0 = __shfl(s, j);
      float wg0 = __shfl(wg, j);
      float e0h[NH];
#pragma unroll
      for (int h = 0; h < NH; h++) e0h[h] = __shfl(exh[h], j);
      const __bf16* r0 = xwb + (size_t)s0 * GATD + lane;
      const __bf16* p0 = xwgb + (size_t)s0 * 128;
#pragma unroll
      for (int h = 0; h < NH; h++) acc[h] += e0h[h] * (float)r0[h * OUTD];
      g0 += wg0 * (float)p0[lane];
      g1 += wg0 * (float)p0[lane + 64];
    }
  }
#pragma unroll
  for (int h = 0; h < NH; h++) {
    float d = denp[h];
    for (int off = 32; off; off >>= 1) d += __shfl_xor(d, off);
    d += exs[h];
    float v = acc[h] / d + (float)bgat[h * OUTD + lane];
    v = lrelu(v, 0.01f);
    h1b[(size_t)i * GATD + h * OUTD + lane] = (__bf16)v;
    out[(size_t)i * ODIM + h * OUTD + lane] = tanhf(v);
  }
  float di = dgcn[i];
  float v0 = lrelu(di * g0 + di * di * (float)xwgb[(size_t)i * 128 + lane] + (float)b0[lane], 0.01f);
  float v1 = lrelu(di * g1 + di * di * (float)xwgb[(size_t)i * 128 + 64 + lane] + (float)b1[lane], 0.01f);
  out[(size_t)i * ODIM + 384 + lane] = tanhf(v0);
  out[(size_t)i * ODIM + 448 + lane] = tanhf(v1);
}

// ---------- ARMA gather: wave per node, shuffle broadcast, 8-edge unroll ----------
__global__ __launch_bounds__(256) void k_arma(const __bf16* __restrict__ trb,
    const int* __restrict__ rowstart, const int* __restrict__ csr_src,
    const float* __restrict__ csr_w, const float* __restrict__ darma,
    const __bf16* __restrict__ ba, float* __restrict__ out) {
  int wv = threadIdx.x >> 6, lane = threadIdx.x & 63;
  int i = blockIdx.x * 4 + wv;
  int e0 = rowstart[i], e1 = rowstart[i + 1];
  int nch = (e1 - e0 + 63) >> 6;
  float aa = 0.f;
  for (int c = 0; c < nch; c++) {
    int base = e0 + c * 64;
    int cnt = e1 - base; cnt = cnt > 64 ? 64 : cnt;
    int s = i; float wav = 0.f;           // register padding: (src=i, w=0)
    if (lane < cnt) {
      int eidx = base + lane;
      s = csr_src[eidx];
      wav = darma[s] * csr_w[eidx];
    }
    int cntp = (cnt + 7) & ~7;
    for (int j = 0; j < cntp; j += 8) {
      int sq[8]; float wq[8];
#pragma unroll
      for (int q = 0; q < 8; q++) { sq[q] = __shfl(s, j + q); wq[q] = __shfl(wav, j + q); }
      float tq[8];
#pragma unroll
      for (int q = 0; q < 8; q++)
        tq[q] = (float)trb[(size_t)sq[q] * 128 + lane];
#pragma unroll
      for (int q = 0; q < 8; q++) aa += wq[q] * tq[q];
    }
  }
  float va = darma[i] * aa + (float)trb[(size_t)i * 128 + 64 + lane] + (float)ba[lane];
  va = fmaxf(va, 0.f);
  out[(size_t)i * ODIM + 512 + lane] = tanhf(va);
}

extern "C" void kernel_launch(void* const* d_in, const int* in_sizes, int n_in,
                              void* d_out, int out_size, void* d_ws, size_t ws_size,
                              hipStream_t stream) {
  const int* ei = (const int*)d_in[1];
  float* out = (float*)d_out;

  char* ws = (char*)d_ws;
  size_t off = 0;
  auto alloc = [&](size_t bytes) -> void* {
    void* p = ws + off;
    off += (bytes + 255) & ~(size_t)255;
    return p;
  };
  int*    flags    = (int*)alloc(32 * 4);
  int*    deg      = (int*)alloc((size_t)3 * NN * 4);
  int*    cursor   = deg + NN;
  float*  wdeg     = (float*)(deg + 2 * NN);
  int*    bsum     = (int*)alloc(128 * 4);
  int*    rowstart = (int*)alloc((size_t)(NN + 1) * 4);
  int*    csr_src  = (int*)alloc((size_t)EE * 4);
  float*  csr_w    = (float*)alloc((size_t)EE * 4);
  float*  dgcn     = (float*)alloc((size_t)NN * 4);
  float*  darma    = (float*)alloc((size_t)NN * 4);
  float*  al       = (float*)alloc((size_t)NN * NH * 4);
  float*  ar       = (float*)alloc((size_t)NN * NH * 4);
  __bf16* bpb   = (__bf16*)alloc(256 * 2);
  __bf16* asb   = (__bf16*)alloc(384 * 2);
  __bf16* adb   = (__bf16*)alloc(384 * 2);
  __bf16* bgatb = (__bf16*)alloc(384 * 2);
  __bf16* bg0b  = (__bf16*)alloc(64 * 2);
  __bf16* bg1b  = (__bf16*)alloc(64 * 2);
  __bf16* bab   = (__bf16*)alloc(64 * 2);
  __bf16* Wp_t    = (__bf16*)alloc(256 * 256 * 2);
  __bf16* Wcat_t  = (__bf16*)alloc((size_t)(384 + 128) * 256 * 2);
  __bf16* Wgat_t  = Wcat_t;
  __bf16* Wg01_t  = Wcat_t + (size_t)384 * 256;
  __bf16* Warma_t = (__bf16*)alloc(128 * 384 * 2);
  char* regA = (char*)alloc((size_t)NN * GATD * 2);
  __bf16* h   = (__bf16*)regA;   // dead after fused gemm
  __bf16* h1b = (__bf16*)regA;
  char* regB = (char*)alloc((size_t)NN * GATD * 2);
  __bf16* xwb = (__bf16*)regB;   // dead after k_gatgcn
  __bf16* trb = (__bf16*)regB;
  __bf16* xwgb = (__bf16*)alloc((size_t)NN * 128 * 2);
  (void)ws_size; (void)in_sizes; (void)n_in; (void)out_size;

  hipMemsetAsync(ws, 0, 256 + (size_t)3 * NN * 4, stream);

  dim3 tb(256);
  // fused probes
  ProbeArgs pa;
  const int pidx[15] = {0, 2, 3, 4, 5, 6, 7, 8, 9, 10, 11, 12, 13, 14, 15};
  const int pcnt[15] = {NN * 256, EE, 256 * 256, 256, 256 * 384, NH * OUTD, NH * OUTD,
                        NH * OUTD, 256 * 64, 64, 256 * 64, 64, GATD * OUTD, GATD * OUTD, 64};
  for (int k = 0; k < 15; k++) { pa.ptr[k] = d_in[pidx[k]]; pa.cnt[k] = pcnt[k]; pa.flagidx[k] = pidx[k]; }
  pa.ei = ei;
  k_probe_all<<<dim3(16), tb, 0, stream>>>(pa, flags);

  // merged conversions
  CvtArgs ca;
  TArgs ta;
  int cvtblk = 0, tblk = 0;
  {
    struct { int idx; __bf16* out; int n; } cv[7] = {
      {4, bpb, 256}, {6, asb, 384}, {7, adb, 384}, {8, bgatb, 384},
      {10, bg0b, 64}, {12, bg1b, 64}, {15, bab, 64},
    };
    for (int k = 0; k < 7; k++) {
      ca.s[k].in = d_in[cv[k].idx]; ca.s[k].out = cv[k].out; ca.s[k].n = cv[k].n;
      ca.s[k].flagidx = cv[k].idx; ca.s[k].blk0 = cvtblk;
      cvtblk += (cv[k].n + 255) / 256;
    }
    struct { int idx; __bf16* out; int R; int C; } tv[6] = {
      {3,  Wp_t,             256, 256},
      {5,  Wgat_t,           256, 384},
      {9,  Wg01_t,           256, 64},
      {11, Wg01_t + 64 * 256, 256, 64},
      {13, Warma_t,          384, 64},
      {14, Warma_t + 64 * 384, 384, 64},
    };
    for (int k = 0; k < 6; k++) {
      ta.s[k].in = d_in[tv[k].idx]; ta.s[k].out = tv[k].out;
      ta.s[k].R = tv[k].R; ta.s[k].C = tv[k].C;
      ta.s[k].flagidx = tv[k].idx; ta.s[k].blk0 = tblk;
      tblk += ((tv[k].R + 31) / 32) * ((tv[k].C + 31) / 32);
    }
    k_cvt_merged<<<dim3(cvtblk + tblk), tb, 0, stream>>>(ca, cvtblk, ta, flags);
  }

  // CSR by dst + degree norms (parallel coalesced scan)
  const int NBLK = (NN + 255) / 256;  // 79
  k_count<<<dim3((EE + 255) / 256), tb, 0, stream>>>(ei, d_in[2], flags, deg, wdeg);
  k_scan1<<<dim3(NBLK), tb, 0, stream>>>(deg, bsum);
  k_scan2<<<dim3(NBLK), tb, 0, stream>>>(deg, bsum, wdeg, rowstart, dgcn, darma);
  k_fill<<<dim3((EE + 255) / 256), tb, 0, stream>>>(ei, d_in[2], flags, rowstart, cursor, csr_src, csr_w);

  const int MB64 = (NN + 63) / 64;  // 313
  // h = x @ Wp + bp   (N=256 -> 2 col-128 blocks)
  gemm64<true ><<<dim3(MB64, 2), tb, 0, stream>>>(d_in[0], &flags[0], Wp_t, bpb,
                                                  h, 256, 256, nullptr, 0, NN, 256);
  // fused: xwb = h @ Wgat (cols 0..383), xwgb = h @ Wgcn01 (cols 384..511)
  gemm64<false><<<dim3(MB64, 4), tb, 0, stream>>>(h, &flags[30], Wcat_t, nullptr,
                                                  xwb, 384, 384, xwgb, 128, NN, 256);
  k_alar_w<<<dim3((NN * NH + 3) / 4), tb, 0, stream>>>(xwb, asb, adb, al, ar);
  // h dead; h1b overwrites region A. GAT + GCN0/1 in one CSR pass.
  k_gatgcn<<<dim3(NN / 4), tb, 0, stream>>>(xwb, xwgb, al, ar, rowstart, csr_src,
                                            csr_w, dgcn, bgatb, bg0b, bg1b, h1b, out);
  // xwb dead; trb overwrites region B   (N=128 -> 1 block)
  gemm64<false><<<dim3(MB64, 1), tb, 0, stream>>>(h1b, &flags[30], Warma_t, nullptr,
                                                  trb, 128, 128, nullptr, 0, NN, 384);
  k_arma<<<dim3(NN / 4), tb, 0, stream>>>(trb, rowstart, csr_src, csr_w,
                                          darma, bab, out);
}

// Round 9
// 284.582 us; speedup vs baseline: 1.0655x; 1.0655x over previous
//
#include <hip/hip_runtime.h>

// R21: gathers reverted VERBATIM to R19 (measured best; R20's __shfl =
// ds_bpermute on CDNA, regressed). New: independent kernels merged into single
// launches via blockIdx split so latency-bound CSR work hides under compute:
//   launch3 = cvt + count, launch5 = gemm1 + scan2, launch6 = gemm2f + fill.
// GEMM body unchanged (device fn). 9 kernel launches + 1 memset.

#define NN 20000
#define EE 320000
#define GATD 384
#define NH 6
#define OUTD 64
#define ODIM 576

typedef __bf16 bf16_8 __attribute__((ext_vector_type(8)));
typedef float f32_4 __attribute__((ext_vector_type(4)));

__device__ __forceinline__ float lrelu(float x, float s) { return x > 0.f ? x : s * x; }

__device__ __forceinline__ float loadf(const void* p, size_t i, int f32) {
  return f32 ? ((const float*)p)[i] : (float)((const __bf16*)p)[i];
}

// ---------- fused dtype probes ----------
struct ProbeArgs {
  const void* ptr[15];
  int cnt[15];
  int flagidx[15];
  const int* ei;
};
__global__ void k_probe_all(ProbeArgs a, int* __restrict__ flags) {
  __shared__ int cnt;
  if (threadIdx.x == 0) cnt = 0;
  __syncthreads();
  int b = blockIdx.x;
  if (b < 15) {
    const unsigned short* u = (const unsigned short*)a.ptr[b];
    int m = a.cnt[b] < 2048 ? a.cnt[b] : 2048;
    int c = 0;
    for (int i = threadIdx.x; i < m; i += 256) {
      float v = __uint_as_float(((unsigned int)u[i]) << 16);
      if (!(fabsf(v) < 1e4f)) c++;
    }
    if (c) atomicAdd(&cnt, c);
    __syncthreads();
    if (threadIdx.x == 0) flags[a.flagidx[b]] = (cnt > m / 16) ? 1 : 0;
  } else {
    int c = 0;
    for (int i = threadIdx.x; i < 1024; i += 256)
      if (a.ei[2 * i + 1] != 0) c++;
    if (c) atomicAdd(&cnt, c);
    __syncthreads();
    if (threadIdx.x == 0) flags[16] = (cnt <= 2) ? 1 : 0;
  }
}

// ---------- merged: small conversions + weight cvt/transpose + k_count ----------
struct CvtSeg { const void* in; __bf16* out; int n; int flagidx; int blk0; };
struct CvtArgs { CvtSeg s[7]; };
struct TSeg { const void* in; __bf16* out; int R; int C; int flagidx; int blk0; };
struct TArgs { TSeg s[6]; };
__global__ __launch_bounds__(256) void k_cvt_count(CvtArgs ca, int ncvtblk, TArgs ta, int ncvtT,
    const int* __restrict__ flags, const int* __restrict__ ei, const void* __restrict__ ew,
    int* __restrict__ deg, float* __restrict__ wdeg) {
  int bx = blockIdx.x;
  if (bx >= ncvtT) {
    // ---- k_count ----
    int e = (bx - ncvtT) * 256 + threadIdx.x;
    if (e >= EE) return;
    int sh = flags[16];
    int d = ei[(size_t)(EE + e) << sh];
    atomicAdd(&deg[d], 1);
    atomicAdd(&wdeg[d], loadf(ew, e, flags[2]));
    return;
  }
  if (bx < ncvtblk) {
    int b = bx;
    int k = 0;
    while (k + 1 < 7 && ca.s[k + 1].blk0 <= b) k++;
    const CvtSeg sg = ca.s[k];
    int i = (b - sg.blk0) * 256 + threadIdx.x;
    if (i >= sg.n) return;
    sg.out[i] = flags[sg.flagidx] ? (__bf16)((const float*)sg.in)[i] : ((const __bf16*)sg.in)[i];
    return;
  }
  __shared__ float t[32][33];
  int b = bx - ncvtblk;
  int k = 0;
  while (k + 1 < 6 && ta.s[k + 1].blk0 <= b) k++;
  const TSeg sg = ta.s[k];
  int f32 = flags[sg.flagidx];
  int tpx = (sg.C + 31) >> 5;
  int lt = b - sg.blk0;
  int c0 = (lt % tpx) * 32, r0 = (lt / tpx) * 32;
  int tid = threadIdx.x;
  for (int idx = tid; idx < 1024; idx += 256) {
    int r = idx >> 5, c = idx & 31;
    if (r0 + r < sg.R && c0 + c < sg.C)
      t[r][c] = loadf(sg.in, (size_t)(r0 + r) * sg.C + (c0 + c), f32);
  }
  __syncthreads();
  for (int idx = tid; idx < 1024; idx += 256) {
    int r = idx >> 5, c = idx & 31;
    if (c0 + r < sg.C && r0 + c < sg.R)
      sg.out[(size_t)(c0 + r) * sg.R + (r0 + c)] = (__bf16)t[c][r];
  }
}

// parallel coalesced scan, phase 1: per-block sums of deg
__global__ __launch_bounds__(256) void k_scan1(const int* __restrict__ deg,
                                               int* __restrict__ bsum) {
  int i = blockIdx.x * 256 + threadIdx.x;
  int v = (i < NN) ? deg[i] : 0;
  for (int off = 32; off; off >>= 1) v += __shfl_xor(v, off);
  __shared__ int ws[4];
  if ((threadIdx.x & 63) == 0) ws[threadIdx.x >> 6] = v;
  __syncthreads();
  if (threadIdx.x == 0) bsum[blockIdx.x] = ws[0] + ws[1] + ws[2] + ws[3];
}

// ---------- scan2 body (device fn) ----------
__device__ __forceinline__ void scan2_body(int b, const int* __restrict__ deg,
    const int* __restrict__ bsum, const float* __restrict__ wdeg,
    int* __restrict__ rowstart, float* __restrict__ dg, float* __restrict__ da) {
  int tid = threadIdx.x;
  int lane = tid & 63, wv = tid >> 6;
  int i = b * 256 + tid;
  __shared__ int red[4];
  __shared__ int wsum2[4];
  __shared__ int sbase;
  {
    int v = (tid < b) ? bsum[tid] : 0;
    for (int off = 32; off; off >>= 1) v += __shfl_xor(v, off);
    if (lane == 0) red[wv] = v;
    __syncthreads();
    if (tid == 0) sbase = red[0] + red[1] + red[2] + red[3];
    __syncthreads();
  }
  int v = (i < NN) ? deg[i] : 0;
  int run = v;
  for (int off = 1; off < 64; off <<= 1) {
    int u = __shfl_up(run, off);
    if (lane >= off) run += u;
  }
  if (lane == 63) wsum2[wv] = run;
  __syncthreads();
  int wb = 0;
#pragma unroll
  for (int w = 0; w < 4; w++) { int x = wsum2[w]; if (w < wv) wb += x; }
  int excl = sbase + wb + run - v;
  if (i < NN) rowstart[i] = excl;
  if (i == NN - 1) rowstart[NN] = excl + v;
  if (i < NN) {
    float w = wdeg[i];
    dg[i] = rsqrtf(w + 1.0f);
    da[i] = w > 0.f ? rsqrtf(w) : 0.f;
  }
}

// ---------- fill body (device fn) ----------
__device__ __forceinline__ void fill_body(int b, const int* __restrict__ ei,
    const void* __restrict__ ew, const int* __restrict__ flags,
    const int* __restrict__ rowstart, int* __restrict__ cursor,
    int* __restrict__ csr_src, float* __restrict__ csr_w) {
  int e = b * 256 + threadIdx.x;
  if (e >= EE) return;
  int sh = flags[16];
  int d = ei[(size_t)(EE + e) << sh];
  int s = ei[(size_t)e << sh];
  int pos = rowstart[d] + atomicAdd(&cursor[d], 1);
  csr_src[pos] = s;
  csr_w[pos] = loadf(ew, e, flags[2]);
}

// ---------- MFMA GEMM body: 64x128 tile, dual output (R16 logic, device fn) ----------
__device__ __forceinline__ void gemm_body(const void* __restrict__ A,
    const int* __restrict__ aflag, const __bf16* __restrict__ Bt,
    const __bf16* __restrict__ bias,
    __bf16* __restrict__ C1, int n1, int ldc1,
    __bf16* __restrict__ C2, int ldc2,
    int M, int K, int bx, int by) {
  __shared__ __bf16 Al[64][40];
  __shared__ __bf16 Bl[128][40];
  int a32 = *aflag;
  int tid = threadIdx.x;
  int w = tid >> 6, lane = tid & 63;
  int quad = lane >> 4, r = lane & 15;
  int row0 = bx * 64, col0 = by * 128;
  f32_4 acc[4][2] = {};
  int srow = tid >> 2;
  int koff = (tid & 3) * 8;
  int brow = tid >> 1;
  int bko  = (tid & 1) * 16;
  for (int kt = 0; kt < K; kt += 32) {
    int arow = row0 + srow;
    if (a32) {
      float4 a0 = {0.f, 0.f, 0.f, 0.f}, a1 = {0.f, 0.f, 0.f, 0.f};
      if (arow < M) {
        const float* ap = (const float*)A + (size_t)arow * K + kt + koff;
        a0 = *(const float4*)ap;
        a1 = *(const float4*)(ap + 4);
      }
      bf16_8 t;
      t[0] = (__bf16)a0.x; t[1] = (__bf16)a0.y; t[2] = (__bf16)a0.z; t[3] = (__bf16)a0.w;
      t[4] = (__bf16)a1.x; t[5] = (__bf16)a1.y; t[6] = (__bf16)a1.z; t[7] = (__bf16)a1.w;
      *(bf16_8*)(&Al[srow][koff]) = t;
    } else {
      float4 av = {0.f, 0.f, 0.f, 0.f};
      if (arow < M) av = *(const float4*)((const __bf16*)A + (size_t)arow * K + kt + koff);
      *(float4*)(&Al[srow][koff]) = av;
    }
    const __bf16* bp = Bt + (size_t)(col0 + brow) * K + kt + bko;
    *(float4*)(&Bl[brow][bko])     = *(const float4*)bp;
    *(float4*)(&Bl[brow][bko + 8]) = *(const float4*)(bp + 8);
    __syncthreads();
    bf16_8 bfrag0 = *(const bf16_8*)(&Bl[w * 16 + r][quad * 8]);
    bf16_8 bfrag1 = *(const bf16_8*)(&Bl[64 + w * 16 + r][quad * 8]);
#pragma unroll
    for (int mt = 0; mt < 4; mt++) {
      bf16_8 afrag = *(const bf16_8*)(&Al[mt * 16 + r][quad * 8]);
      acc[mt][0] = __builtin_amdgcn_mfma_f32_16x16x32_bf16(afrag, bfrag0, acc[mt][0], 0, 0, 0);
      acc[mt][1] = __builtin_amdgcn_mfma_f32_16x16x32_bf16(afrag, bfrag1, acc[mt][1], 0, 0, 0);
    }
    __syncthreads();
  }
  __bf16* Cp; int ldc; int cbase;
  if (col0 < n1) { Cp = C1; ldc = ldc1; cbase = col0; }
  else           { Cp = C2; ldc = ldc2; cbase = col0 - n1; }
  int cc0 = cbase + w * 16 + r;
  int cc1 = cbase + 64 + w * 16 + r;
  float bv0 = bias ? (float)bias[col0 + w * 16 + r] : 0.0f;
  float bv1 = bias ? (float)bias[col0 + 64 + w * 16 + r] : 0.0f;
#pragma unroll
  for (int mt = 0; mt < 4; mt++) {
#pragma unroll
    for (int rr = 0; rr < 4; rr++) {
      int crow = row0 + mt * 16 + quad * 4 + rr;
      if (crow < M) {
        Cp[(size_t)crow * ldc + cc0] = (__bf16)(acc[mt][0][rr] + bv0);
        Cp[(size_t)crow * ldc + cc1] = (__bf16)(acc[mt][1][rr] + bv1);
      }
    }
  }
}

// plain GEMM launch wrapper (gemm4)
__global__ __launch_bounds__(256) void k_gemm(const void* __restrict__ A,
    const int* __restrict__ aflag, const __bf16* __restrict__ Bt,
    const __bf16* __restrict__ bias,
    __bf16* __restrict__ C1, int n1, int ldc1,
    __bf16* __restrict__ C2, int ldc2, int M, int K) {
  gemm_body(A, aflag, Bt, bias, C1, n1, ldc1, C2, ldc2, M, K, blockIdx.x, blockIdx.y);
}

// merged: gemm1 (626 blocks first) + scan2 (79 blocks)
__global__ __launch_bounds__(256) void k_gemm1_scan2(const void* __restrict__ A,
    const int* __restrict__ aflag, const __bf16* __restrict__ Bt,
    const __bf16* __restrict__ bias, __bf16* __restrict__ C1, int M, int K, int ngemm,
    const int* __restrict__ deg, const int* __restrict__ bsum,
    const float* __restrict__ wdeg, int* __restrict__ rowstart,
    float* __restrict__ dg, float* __restrict__ da) {
  int bx = blockIdx.x;
  if (bx < ngemm) {
    gemm_body(A, aflag, Bt, bias, C1, 256, 256, nullptr, 0, M, K, bx % 313, bx / 313);
  } else {
    scan2_body(bx - ngemm, deg, bsum, wdeg, rowstart, dg, da);
  }
}

// merged: gemm2f (1252 blocks first) + fill (1250 blocks)
__global__ __launch_bounds__(256) void k_gemm2_fill(const void* __restrict__ A,
    const int* __restrict__ aflag, const __bf16* __restrict__ Bt,
    __bf16* __restrict__ C1, int n1, int ldc1, __bf16* __restrict__ C2, int ldc2,
    int M, int K, int ngemm,
    const int* __restrict__ ei, const void* __restrict__ ew,
    const int* __restrict__ flags, const int* __restrict__ rowstart,
    int* __restrict__ cursor, int* __restrict__ csr_src, float* __restrict__ csr_w) {
  int bx = blockIdx.x;
  if (bx < ngemm) {
    gemm_body(A, aflag, Bt, nullptr, C1, n1, ldc1, C2, ldc2, M, K, bx % 313, bx / 313);
  } else {
    fill_body(bx - ngemm, ei, ew, flags, rowstart, cursor, csr_src, csr_w);
  }
}

// ---------- attention logits: wave per (node,head) ---------- (R12 verbatim)
__global__ void k_alar_w(const __bf16* __restrict__ xwb, const __bf16* __restrict__ as_,
                         const __bf16* __restrict__ ad_,
                         float* __restrict__ al, float* __restrict__ ar) {
  int p = blockIdx.x * 4 + (threadIdx.x >> 6);
  int lane = threadIdx.x & 63;
  if (p >= NN * NH) return;
  int i = p / NH, h = p - i * NH;
  float xv = (float)xwb[(size_t)i * GATD + h * OUTD + lane];
  float s1 = xv * (float)as_[h * OUTD + lane];
  float s2 = xv * (float)ad_[h * OUTD + lane];
  for (int off = 32; off; off >>= 1) { s1 += __shfl_xor(s1, off); s2 += __shfl_xor(s2, off); }
  if (lane == 0) { al[p] = s1; ar[p] = s2; }
}

// ---------- fused GAT + GCN0/1: wave per node, single CSR pass ---------- (R19 verbatim)
__global__ __launch_bounds__(256) void k_gatgcn(const __bf16* __restrict__ xwb,
    const __bf16* __restrict__ xwgb,
    const float* __restrict__ al, const float* __restrict__ ar,
    const int* __restrict__ rowstart, const int* __restrict__ csr_src,
    const float* __restrict__ csr_w, const float* __restrict__ dgcn,
    const __bf16* __restrict__ bgat, const __bf16* __restrict__ b0,
    const __bf16* __restrict__ b1,
    __bf16* __restrict__ h1b, float* __restrict__ out) {
  int wv = threadIdx.x >> 6, lane = threadIdx.x & 63;
  int i = blockIdx.x * 4 + wv;           // NN % 4 == 0
  __shared__ int   src_sh[4][64];
  __shared__ float ex_sh[4][64][NH];
  __shared__ float wg_sh[4][64];
  __shared__ int   mc_sh[4];
  int e0 = rowstart[i], e1 = rowstart[i + 1];
  if (lane == 0) mc_sh[wv] = (e1 - e0 + 63) >> 6;
  float arv[NH], exs[NH], acc[NH], denp[NH];
#pragma unroll
  for (int h = 0; h < NH; h++) arv[h] = ar[i * NH + h];
#pragma unroll
  for (int h = 0; h < NH; h++) {
    float e = lrelu(al[i * NH + h] + arv[h], 0.2f);
    exs[h] = __expf(e);                  // self-loop weight
    acc[h] = exs[h] * (float)xwb[(size_t)i * GATD + h * OUTD + lane];
    denp[h] = 0.f;
  }
  float g0 = 0.f, g1 = 0.f;
  __syncthreads();
  int mch = max(max(mc_sh[0], mc_sh[1]), max(mc_sh[2], mc_sh[3]));
  for (int c = 0; c < mch; c++) {
    if (c) __syncthreads();
    int base = e0 + c * 64;
    int cnt = e1 - base; cnt = cnt < 0 ? 0 : (cnt > 64 ? 64 : cnt);
    if (lane < cnt) {
      int eidx = base + lane;
      int s = csr_src[eidx];
      src_sh[wv][lane] = s;
      wg_sh[wv][lane] = dgcn[s] * csr_w[eidx];
#pragma unroll
      for (int h = 0; h < NH; h++) {
        float ex = __expf(lrelu(al[s * NH + h] + arv[h], 0.2f));
        ex_sh[wv][lane][h] = ex;
        denp[h] += ex;
      }
    }
    __syncthreads();
    int j = 0;
    for (; j + 2 <= cnt; j += 2) {
      int s0 = src_sh[wv][j], s1 = src_sh[wv][j + 1];
      const __bf16* r0 = xwb + (size_t)s0 * GATD + lane;
      const __bf16* r1 = xwb + (size_t)s1 * GATD + lane;
      const __bf16* p0 = xwgb + (size_t)s0 * 128;
      const __bf16* p1 = xwgb + (size_t)s1 * 128;
      float x0[NH], x1[NH];
#pragma unroll
      for (int h = 0; h < NH; h++) { x0[h] = (float)r0[h * OUTD]; x1[h] = (float)r1[h * OUTD]; }
      float y00 = (float)p0[lane], y01 = (float)p0[lane + 64];
      float y10 = (float)p1[lane], y11 = (float)p1[lane + 64];
      float wg0 = wg_sh[wv][j], wg1 = wg_sh[wv][j + 1];
#pragma unroll
      for (int h = 0; h < NH; h++)
        acc[h] += ex_sh[wv][j][h] * x0[h] + ex_sh[wv][j + 1][h] * x1[h];
      g0 += wg0 * y00 + wg1 * y10;
      g1 += wg0 * y01 + wg1 * y11;
    }
    if (j < cnt) {
      int s0 = src_sh[wv][j];
      const __bf16* r0 = xwb + (size_t)s0 * GATD + lane;
      const __bf16* p0 = xwgb + (size_t)s0 * 128;
      float wg0 = wg_sh[wv][j];
#pragma unroll
      for (int h = 0; h < NH; h++) acc[h] += ex_sh[wv][j][h] * (float)r0[h * OUTD];
      g0 += wg0 * (float)p0[lane];
      g1 += wg0 * (float)p0[lane + 64];
    }
  }
#pragma unroll
  for (int h = 0; h < NH; h++) {
    float d = denp[h];
    for (int off = 32; off; off >>= 1) d += __shfl_xor(d, off);
    d += exs[h];
    float v = acc[h] / d + (float)bgat[h * OUTD + lane];
    v = lrelu(v, 0.01f);
    h1b[(size_t)i * GATD + h * OUTD + lane] = (__bf16)v;
    out[(size_t)i * ODIM + h * OUTD + lane] = tanhf(v);
  }
  float di = dgcn[i];
  float v0 = lrelu(di * g0 + di * di * (float)xwgb[(size_t)i * 128 + lane] + (float)b0[lane], 0.01f);
  float v1 = lrelu(di * g1 + di * di * (float)xwgb[(size_t)i * 128 + 64 + lane] + (float)b1[lane], 0.01f);
  out[(size_t)i * ODIM + 384 + lane] = tanhf(v0);
  out[(size_t)i * ODIM + 448 + lane] = tanhf(v1);
}

// ---------- ARMA gather: wave per node, 8-edge unroll, padded staging ---------- (R19 verbatim)
__global__ __launch_bounds__(256) void k_arma(const __bf16* __restrict__ trb,
    const int* __restrict__ rowstart, const int* __restrict__ csr_src,
    const float* __restrict__ csr_w, const float* __restrict__ darma,
    const __bf16* __restrict__ ba, float* __restrict__ out) {
  int wv = threadIdx.x >> 6, lane = threadIdx.x & 63;
  int i = blockIdx.x * 4 + wv;
  __shared__ __attribute__((aligned(16))) int   src_sh[4][64];
  __shared__ __attribute__((aligned(16))) float wa_sh[4][64];
  __shared__ int mc_sh[4];
  int e0 = rowstart[i], e1 = rowstart[i + 1];
  if (lane == 0) mc_sh[wv] = (e1 - e0 + 63) >> 6;
  __syncthreads();
  int mch = max(max(mc_sh[0], mc_sh[1]), max(mc_sh[2], mc_sh[3]));
  float aa = 0.f;
  for (int c = 0; c < mch; c++) {
    if (c) __syncthreads();
    int base = e0 + c * 64;
    int cnt = e1 - base; cnt = cnt < 0 ? 0 : (cnt > 64 ? 64 : cnt);
    int s = i; float wav = 0.f;           // padding: (src=i, w=0) contributes 0
    if (lane < cnt) {
      int eidx = base + lane;
      s = csr_src[eidx];
      wav = darma[s] * csr_w[eidx];
    }
    src_sh[wv][lane] = s;
    wa_sh[wv][lane] = wav;
    __syncthreads();
    int cntp = (cnt + 7) & ~7;
    for (int j = 0; j < cntp; j += 8) {
      int4 sa = *(const int4*)&src_sh[wv][j];
      int4 sb = *(const int4*)&src_sh[wv][j + 4];
      int sq[8] = {sa.x, sa.y, sa.z, sa.w, sb.x, sb.y, sb.z, sb.w};
      float tq[8];
#pragma unroll
      for (int q = 0; q < 8; q++)
        tq[q] = (float)trb[(size_t)sq[q] * 128 + lane];
      float4 wa0 = *(const float4*)&wa_sh[wv][j];
      float4 wa1 = *(const float4*)&wa_sh[wv][j + 4];
      float waq[8] = {wa0.x, wa0.y, wa0.z, wa0.w, wa1.x, wa1.y, wa1.z, wa1.w};
#pragma unroll
      for (int q = 0; q < 8; q++) aa += waq[q] * tq[q];
    }
  }
  float va = darma[i] * aa + (float)trb[(size_t)i * 128 + 64 + lane] + (float)ba[lane];
  va = fmaxf(va, 0.f);
  out[(size_t)i * ODIM + 512 + lane] = tanhf(va);
}

extern "C" void kernel_launch(void* const* d_in, const int* in_sizes, int n_in,
                              void* d_out, int out_size, void* d_ws, size_t ws_size,
                              hipStream_t stream) {
  const int* ei = (const int*)d_in[1];
  float* out = (float*)d_out;

  char* ws = (char*)d_ws;
  size_t off = 0;
  auto alloc = [&](size_t bytes) -> void* {
    void* p = ws + off;
    off += (bytes + 255) & ~(size_t)255;
    return p;
  };
  int*    flags    = (int*)alloc(32 * 4);
  int*    deg      = (int*)alloc((size_t)3 * NN * 4);
  int*    cursor   = deg + NN;
  float*  wdeg     = (float*)(deg + 2 * NN);
  int*    bsum     = (int*)alloc(128 * 4);
  int*    rowstart = (int*)alloc((size_t)(NN + 1) * 4);
  int*    csr_src  = (int*)alloc((size_t)EE * 4);
  float*  csr_w    = (float*)alloc((size_t)EE * 4);
  float*  dgcn     = (float*)alloc((size_t)NN * 4);
  float*  darma    = (float*)alloc((size_t)NN * 4);
  float*  al       = (float*)alloc((size_t)NN * NH * 4);
  float*  ar       = (float*)alloc((size_t)NN * NH * 4);
  __bf16* bpb   = (__bf16*)alloc(256 * 2);
  __bf16* asb   = (__bf16*)alloc(384 * 2);
  __bf16* adb   = (__bf16*)alloc(384 * 2);
  __bf16* bgatb = (__bf16*)alloc(384 * 2);
  __bf16* bg0b  = (__bf16*)alloc(64 * 2);
  __bf16* bg1b  = (__bf16*)alloc(64 * 2);
  __bf16* bab   = (__bf16*)alloc(64 * 2);
  __bf16* Wp_t    = (__bf16*)alloc(256 * 256 * 2);
  __bf16* Wcat_t  = (__bf16*)alloc((size_t)(384 + 128) * 256 * 2);
  __bf16* Wgat_t  = Wcat_t;
  __bf16* Wg01_t  = Wcat_t + (size_t)384 * 256;
  __bf16* Warma_t = (__bf16*)alloc(128 * 384 * 2);
  char* regA = (char*)alloc((size_t)NN * GATD * 2);
  __bf16* h   = (__bf16*)regA;   // dead after gemm2f
  __bf16* h1b = (__bf16*)regA;
  char* regB = (char*)alloc((size_t)NN * GATD * 2);
  __bf16* xwb = (__bf16*)regB;   // dead after k_gatgcn
  __bf16* trb = (__bf16*)regB;
  __bf16* xwgb = (__bf16*)alloc((size_t)NN * 128 * 2);
  (void)ws_size; (void)in_sizes; (void)n_in; (void)out_size;

  hipMemsetAsync(ws, 0, 256 + (size_t)3 * NN * 4, stream);

  dim3 tb(256);
  // fused probes
  ProbeArgs pa;
  const int pidx[15] = {0, 2, 3, 4, 5, 6, 7, 8, 9, 10, 11, 12, 13, 14, 15};
  const int pcnt[15] = {NN * 256, EE, 256 * 256, 256, 256 * 384, NH * OUTD, NH * OUTD,
                        NH * OUTD, 256 * 64, 64, 256 * 64, 64, GATD * OUTD, GATD * OUTD, 64};
  for (int k = 0; k < 15; k++) { pa.ptr[k] = d_in[pidx[k]]; pa.cnt[k] = pcnt[k]; pa.flagidx[k] = pidx[k]; }
  pa.ei = ei;
  k_probe_all<<<dim3(16), tb, 0, stream>>>(pa, flags);

  // merged conversions + count
  CvtArgs ca;
  TArgs ta;
  int cvtblk = 0, tblk = 0;
  {
    struct { int idx; __bf16* out; int n; } cv[7] = {
      {4, bpb, 256}, {6, asb, 384}, {7, adb, 384}, {8, bgatb, 384},
      {10, bg0b, 64}, {12, bg1b, 64}, {15, bab, 64},
    };
    for (int k = 0; k < 7; k++) {
      ca.s[k].in = d_in[cv[k].idx]; ca.s[k].out = cv[k].out; ca.s[k].n = cv[k].n;
      ca.s[k].flagidx = cv[k].idx; ca.s[k].blk0 = cvtblk;
      cvtblk += (cv[k].n + 255) / 256;
    }
    struct { int idx; __bf16* out; int R; int C; } tv[6] = {
      {3,  Wp_t,             256, 256},
      {5,  Wgat_t,           256, 384},
      {9,  Wg01_t,           256, 64},
      {11, Wg01_t + 64 * 256, 256, 64},
      {13, Warma_t,          384, 64},
      {14, Warma_t + 64 * 384, 384, 64},
    };
    for (int k = 0; k < 6; k++) {
      ta.s[k].in = d_in[tv[k].idx]; ta.s[k].out = tv[k].out;
      ta.s[k].R = tv[k].R; ta.s[k].C = tv[k].C;
      ta.s[k].flagidx = tv[k].idx; ta.s[k].blk0 = tblk;
      tblk += ((tv[k].R + 31) / 32) * ((tv[k].C + 31) / 32);
    }
  }
  const int EEBLK = (EE + 255) / 256;   // 1250
  const int NBLK  = (NN + 255) / 256;   // 79
  const int MB64  = (NN + 63) / 64;     // 313
  int ncvtT = cvtblk + tblk;
  k_cvt_count<<<dim3(ncvtT + EEBLK), tb, 0, stream>>>(ca, cvtblk, ta, ncvtT,
                                                      flags, ei, d_in[2], deg, wdeg);

  k_scan1<<<dim3(NBLK), tb, 0, stream>>>(deg, bsum);

  // gemm1 (h = x @ Wp + bp; 313x2 blocks) + scan2 (79 blocks)
  k_gemm1_scan2<<<dim3(313 * 2 + NBLK), tb, 0, stream>>>(d_in[0], &flags[0], Wp_t, bpb,
      h, NN, 256, 313 * 2, deg, bsum, wdeg, rowstart, dgcn, darma);

  // gemm2f (xwb|xwgb = h @ Wcat; 313x4 blocks) + fill (1250 blocks)
  k_gemm2_fill<<<dim3(313 * 4 + EEBLK), tb, 0, stream>>>(h, &flags[30], Wcat_t,
      xwb, 384, 384, xwgb, 128, NN, 256, 313 * 4,
      ei, d_in[2], flags, rowstart, cursor, csr_src, csr_w);

  k_alar_w<<<dim3((NN * NH + 3) / 4), tb, 0, stream>>>(xwb, asb, adb, al, ar);
  // h dead; h1b overwrites region A. GAT + GCN0/1 in one CSR pass.
  k_gatgcn<<<dim3(NN / 4), tb, 0, stream>>>(xwb, xwgb, al, ar, rowstart, csr_src,
                                            csr_w, dgcn, bgatb, bg0b, bg1b, h1b, out);
  // xwb dead; trb overwrites region B   (N=128 -> 1 block)
  k_gemm<<<dim3(MB64, 1), tb, 0, stream>>>(h1b, &flags[30], Warma_t, nullptr,
                                           trb, 128, 128, nullptr, 0, NN, 384);
  k_arma<<<dim3(NN / 4), tb, 0, stream>>>(trb, rowstart, csr_src, csr_w,
                                          darma, bab, out);
}